// Round 2
// baseline (57.254 us; speedup 1.0000x reference)
//
#include <hip/hip_runtime.h>

#define T_STEPS 512
#define C_CH    128
#define U_LAB   48
#define PF      16

__device__ __forceinline__ float fexp2(float x) {
#if __has_builtin(__builtin_amdgcn_exp2f)
    return __builtin_amdgcn_exp2f(x);   // v_exp_f32
#else
    return __builtin_exp2f(x);
#endif
}
__device__ __forceinline__ float flog2(float x) {
#if __has_builtin(__builtin_amdgcn_logf)
    return __builtin_amdgcn_logf(x);    // v_log_f32
#else
    return __builtin_log2f(x);
#endif
}

// One wave (64 lanes) per batch element.
// Lane tid owns extended-label states s = 2*tid (blank) and s = 2*tid+1 (label tid).
// Log2-domain forward recurrence; single __shfl_up per time step.
__global__ __launch_bounds__(64) void ctc_fwd_kernel(const int* __restrict__ yt,
                                                     const float* __restrict__ yp,
                                                     float* __restrict__ out) {
    const int b   = blockIdx.x;
    const int tid = threadIdx.x;
    const float NEG = -1e30f;
    const float EPS = 1e-7f;

    const bool is_lab = (tid < U_LAB);
    int lab = is_lab ? yt[b * U_LAB + tid] : 0;
    int labprev = __shfl_up(lab, 1);
    const bool allow = (tid >= 1) && is_lab && (lab != labprev); // skip-transition allowed

    const float* __restrict__ base = yp + (size_t)b * T_STEPS * C_CH;

    // t = 0 init: only s=0 (blank) and s=1 (first label) reachable
    float a0, a1;
    {
        float pb = base[C_CH - 1];
        float pl = base[lab];
        a0 = (tid == 0) ? flog2(pb + EPS) : NEG;
        a1 = (tid == 0) ? flog2(pl + EPS) : NEG;
    }

    // register prefetch pipeline: raw probs for t = 1..PF
    float curB[PF], curL[PF];
#pragma unroll
    for (int k = 0; k < PF; ++k) {
        const float* row = base + (size_t)(1 + k) * C_CH;
        curB[k] = row[C_CH - 1];
        curL[k] = row[lab];
    }

    // 31 bodies x 16 steps: t = 1..496 ; prefetch t+16 (clamped) after each use
    int t0 = 1;
    for (int body = 0; body < 31; ++body) {
#pragma unroll
        for (int k = 0; k < PF; ++k) {
            float lpb = flog2(curB[k] + EPS);
            float lpl = flog2(curL[k] + EPS);
            float prev1 = __shfl_up(a1, 1);           // alpha[2*tid - 1]
            if (tid == 0) prev1 = NEG;
            // even state s=2*tid (blank): lse2(a0, prev1) + lpb
            float m0 = fmaxf(a0, prev1);
            float n0 = m0 + flog2(fexp2(a0 - m0) + fexp2(prev1 - m0)) + lpb;
            // odd state s=2*tid+1: lse3(a1, a0, allow ? prev1 : NEG) + lpl
            float c2 = allow ? prev1 : NEG;
            float m1 = fmaxf(fmaxf(a1, a0), c2);
            float n1 = m1 + flog2(fexp2(a1 - m1) + fexp2(a0 - m1) + fexp2(c2 - m1)) + lpl;
            a0 = n0;
            a1 = is_lab ? n1 : NEG;
            // prefetch raw probs for t0 + PF + k (clamped to last row; tail ignores extras)
            int tn = t0 + PF + k;
            tn = (tn < T_STEPS) ? tn : (T_STEPS - 1);
            const float* row = base + (size_t)tn * C_CH;
            curB[k] = row[C_CH - 1];
            curL[k] = row[lab];
        }
        t0 += PF;
    }

    // tail: 15 steps, t = 497..511
#pragma unroll
    for (int k = 0; k < PF - 1; ++k) {
        float lpb = flog2(curB[k] + EPS);
        float lpl = flog2(curL[k] + EPS);
        float prev1 = __shfl_up(a1, 1);
        if (tid == 0) prev1 = NEG;
        float m0 = fmaxf(a0, prev1);
        float n0 = m0 + flog2(fexp2(a0 - m0) + fexp2(prev1 - m0)) + lpb;
        float c2 = allow ? prev1 : NEG;
        float m1 = fmaxf(fmaxf(a1, a0), c2);
        float n1 = m1 + flog2(fexp2(a1 - m1) + fexp2(a0 - m1) + fexp2(c2 - m1)) + lpl;
        a0 = n0;
        a1 = is_lab ? n1 : NEG;
    }

    // total path log-prob ends at s=96 (lane 48, a0) or s=95 (lane 47, a1)
    float v96 = __shfl(a0, 48);
    float v95 = __shfl(a1, 47);
    float m  = fmaxf(v95, v96);
    float ll2 = m + flog2(fexp2(v95 - m) + fexp2(v96 - m));
    if (tid == 0) out[b] = -(ll2 * 0.69314718055994530942f);
}

extern "C" void kernel_launch(void* const* d_in, const int* in_sizes, int n_in,
                              void* d_out, int out_size, void* d_ws, size_t ws_size,
                              hipStream_t stream) {
    const int*   yt  = (const int*)d_in[0];   // y_true [B, 48] int
    const float* yp  = (const float*)d_in[1]; // y_pred [B, 512, 128] f32
    float*       out = (float*)d_out;         // [B, 1] f32
    const int B = in_sizes[0] / U_LAB;        // 256
    ctc_fwd_kernel<<<B, 64, 0, stream>>>(yt, yp, out);
}

// Round 3
// 27.667 us; speedup vs baseline: 2.0694x; 2.0694x over previous
//
#include <hip/hip_runtime.h>

#define T_STEPS 512
#define C_CH    128
#define U_LAB   48
#define PF      16
#define NEGF    (-1e30f)
#define EPSF    (1e-7f)

__device__ __forceinline__ float fexp2(float x) {
#if __has_builtin(__builtin_amdgcn_exp2f)
    return __builtin_amdgcn_exp2f(x);   // v_exp_f32
#else
    return __builtin_exp2f(x);
#endif
}
__device__ __forceinline__ float flog2(float x) {
#if __has_builtin(__builtin_amdgcn_logf)
    return __builtin_amdgcn_logf(x);    // v_log_f32
#else
    return __builtin_log2f(x);
#endif
}

// lane n <- lane n-1 (whole wave), lane 0 <- NEG   (v_mov_b32_dpp wave_shr:1)
__device__ __forceinline__ float dpp_shr1_negfill(float x) {
    int r = __builtin_amdgcn_update_dpp(__builtin_bit_cast(int, NEGF),
                                        __builtin_bit_cast(int, x),
                                        0x138, 0xF, 0xF, false);
    return __builtin_bit_cast(float, r);
}
// lane n <- lane n+1 (whole wave), lane 63 <- NEG  (v_mov_b32_dpp wave_shl:1)
__device__ __forceinline__ float dpp_shl1_negfill(float x) {
    int r = __builtin_amdgcn_update_dpp(__builtin_bit_cast(int, NEGF),
                                        __builtin_bit_cast(int, x),
                                        0x130, 0xF, 0xF, false);
    return __builtin_bit_cast(float, r);
}

// lse2 with one exp + one log: max + log2(1 + 2^(-|x-y|))
__device__ __forceinline__ float lse2f(float x, float y) {
    float m = fmaxf(x, y);
    float d = -fabsf(x - y);
    return m + flog2(1.0f + fexp2(d));
}

// Block = 2 waves per batch element. Lane t owns states s=2t (blank, a0) and
// s=2t+1 (label t, a1). Wave 0: forward alpha t=0..255. Wave 1: emission-
// inclusive backward betaE t=511..255. ll = lse_s(alpha+betaE-lp_255).
__global__ __launch_bounds__(128) void ctc_mitm_kernel(const int* __restrict__ yt,
                                                       const float* __restrict__ yp,
                                                       float* __restrict__ out) {
    __shared__ float s_fa0[64];
    __shared__ float s_fa1[64];

    const int b    = blockIdx.x;
    const int lane = threadIdx.x & 63;
    const int wav  = threadIdx.x >> 6;

    const bool is_lab = (lane < U_LAB);
    const int  lab    = is_lab ? yt[b * U_LAB + lane] : 0;
    const float* __restrict__ base = yp + (size_t)b * T_STEPS * C_CH;

    float a0, a1;

    if (wav == 0) {
        // ---------------- forward: alpha, t = 0 .. 255 ----------------
        int labprev = __builtin_amdgcn_update_dpp(-1, lab, 0x138, 0xF, 0xF, false);
        const bool allow = (lane >= 1) && is_lab && (lab != labprev);

        {
            float pb = base[C_CH - 1];
            float pl = base[lab];
            a0 = (lane == 0) ? flog2(pb + EPSF) : NEGF;
            a1 = (lane == 0) ? flog2(pl + EPSF) : NEGF;
        }

        float curB[PF], curL[PF];
#pragma unroll
        for (int k = 0; k < PF; ++k) {
            const float* row = base + (size_t)(1 + k) * C_CH;
            curB[k] = row[C_CH - 1];
            curL[k] = row[lab];
        }

        int t0 = 1;
#pragma unroll 1
        for (int body = 0; body < 15; ++body) {   // t = 1..240
#pragma unroll
            for (int k = 0; k < PF; ++k) {
                float lpb = flog2(curB[k] + EPSF);
                float lpl = flog2(curL[k] + EPSF);
                float p1  = dpp_shr1_negfill(a1);           // alpha[2t-1]
                float n0  = lse2f(a0, p1) + lpb;
                float c2  = allow ? p1 : NEGF;
                float m1  = fmaxf(fmaxf(a1, a0), c2);
                float n1  = m1 + flog2(fexp2(a1 - m1) + fexp2(a0 - m1) + fexp2(c2 - m1)) + lpl;
                a0 = n0; a1 = n1;
                const float* row = base + (size_t)(t0 + PF + k) * C_CH;  // <= 271, in-bounds
                curB[k] = row[C_CH - 1];
                curL[k] = row[lab];
            }
            t0 += PF;
        }
        // tail: t = 241..255 (15 steps, consume curB/curL[0..14])
#pragma unroll
        for (int k = 0; k < PF - 1; ++k) {
            float lpb = flog2(curB[k] + EPSF);
            float lpl = flog2(curL[k] + EPSF);
            float p1  = dpp_shr1_negfill(a1);
            float n0  = lse2f(a0, p1) + lpb;
            float c2  = allow ? p1 : NEGF;
            float m1  = fmaxf(fmaxf(a1, a0), c2);
            float n1  = m1 + flog2(fexp2(a1 - m1) + fexp2(a0 - m1) + fexp2(c2 - m1)) + lpl;
            a0 = n0; a1 = n1;
        }
        s_fa0[lane] = a0;
        s_fa1[lane] = a1;
    } else {
        // ---------------- backward: betaE, t = 511 .. 255 ----------------
        // betaE_t(s) = lp_t(s) + lse(betaE_{t+1}(s), betaE_{t+1}(s+1), [skip] betaE_{t+1}(s+2))
        // s=2t (blank): lse2(a0, a1) local. s=2t+1: needs a0,a1 of lane t+1.
        int labnext = (lane + 1 < U_LAB) ? yt[b * U_LAB + lane + 1] : -1;
        const bool allowD = (lane + 1 < U_LAB) && (lab != labnext);

        {
            const float* row = base + (size_t)(T_STEPS - 1) * C_CH;
            float pb = row[C_CH - 1];
            float pl = row[lab];
            a0 = (lane == 48) ? flog2(pb + EPSF) : NEGF;  // state 96 (last blank)
            a1 = (lane == 47) ? flog2(pl + EPSF) : NEGF;  // state 95 (last label)
        }

        float curB[PF], curL[PF];
#pragma unroll
        for (int k = 0; k < PF; ++k) {
            const float* row = base + (size_t)(510 - k) * C_CH;
            curB[k] = row[C_CH - 1];
            curL[k] = row[lab];
        }

        int t0 = 510;
#pragma unroll 1
        for (int body = 0; body < 16; ++body) {   // t = 510..255
#pragma unroll
            for (int k = 0; k < PF; ++k) {
                float lpb = flog2(curB[k] + EPSF);
                float lpl = flog2(curL[k] + EPSF);
                float b0  = dpp_shl1_negfill(a0);           // betaE[s+1] for odd s
                float b1  = dpp_shl1_negfill(a1);           // betaE[s+2] for odd s
                float n0  = lse2f(a0, a1) + lpb;            // blank: no skip into blank
                float c2  = allowD ? b1 : NEGF;
                float m1  = fmaxf(fmaxf(a1, b0), c2);
                float n1  = m1 + flog2(fexp2(a1 - m1) + fexp2(b0 - m1) + fexp2(c2 - m1)) + lpl;
                a0 = n0; a1 = n1;
                const float* row = base + (size_t)(t0 - PF - k) * C_CH;  // >= 239, in-bounds
                curB[k] = row[C_CH - 1];
                curL[k] = row[lab];
            }
            t0 -= PF;
        }
    }

    __syncthreads();

    if (wav == 1) {
        // combine at t0 = 255: ll = lse_s( alpha_255(s) + betaE_255(s) - lp_255(s) )
        const float* row = base + (size_t)255 * C_CH;
        float lpb = flog2(row[C_CH - 1] + EPSF);
        float lpl = flog2(row[lab] + EPSF);
        float c0 = s_fa0[lane] + a0 - lpb;
        float c1 = s_fa1[lane] + a1 - lpl;
        float c  = lse2f(c0, c1);
#pragma unroll
        for (int off = 32; off >= 1; off >>= 1)
            c = lse2f(c, __shfl_xor(c, off));
        if (lane == 0) out[b] = -(c * 0.69314718055994530942f);  // log2 -> ln
    }
}

extern "C" void kernel_launch(void* const* d_in, const int* in_sizes, int n_in,
                              void* d_out, int out_size, void* d_ws, size_t ws_size,
                              hipStream_t stream) {
    const int*   yt  = (const int*)d_in[0];   // y_true [B, 48] int
    const float* yp  = (const float*)d_in[1]; // y_pred [B, 512, 128] f32
    float*       out = (float*)d_out;         // [B, 1] f32
    const int B = in_sizes[0] / U_LAB;        // 256
    ctc_mitm_kernel<<<B, 128, 0, stream>>>(yt, yp, out);
}